// Round 17
// baseline (370.476 us; speedup 1.0000x reference)
//
#include <hip/hip_runtime.h>
#include <hip/hip_bf16.h>

#define B_    8
#define NP    2352
#define D_    512
#define SENT  48
#define PAIRS 512
#define NERL  16
#define REL   32
#define MTOT  (B_*NP)   // 18816
#define SLOTB 640       // slots per batch (48 ner + up to 148 pairs * 4)
#define MG    (B_*SLOTB) // 5120 gathered slots = 40 tiles of 128
#define GSCALE 32.0f    // g0 -> fp8 pre-scale (avoids e4m3 denormal region)

typedef unsigned short u16;
typedef unsigned char  u8;
typedef __bf16 bf16x8 __attribute__((ext_vector_type(8)));
typedef float  f32x4  __attribute__((ext_vector_type(4)));

__device__ __forceinline__ u16 f2b(float f) {
  union { float f; unsigned u; } c; c.f = f;
  unsigned u = c.u;
  u += 0x7fffu + ((u >> 16) & 1u);           // round-to-nearest-even
  return (u16)(u >> 16);
}
__device__ __forceinline__ float b2f(u16 h) {
  union { unsigned u; float f; } c; c.u = ((unsigned)h) << 16;
  return c.f;
}
// ---- e4m3fn encode (soft fallback) ----
__device__ __forceinline__ u8 f2f8(float f) {
  unsigned u = __float_as_uint(f);
  u8 s = (u >> 24) & 0x80;
  float a = fabsf(f);
  if (a < 0.0009765625f) return s;            // < 2^-10 -> 0
  if (a >= 448.f) return s | 0x7E;            // clamp to max finite 448
  int e = ((u >> 23) & 0xFF) - 127;
  if (e < -6) {                               // denormal: m * 2^-9
    int q = (int)(a * 512.f + 0.5f);
    if (q >= 8) return s | 0x08;
    return s | (u8)q;
  }
  float sc = __uint_as_float((unsigned)((127 - e) << 23));   // 2^-e
  int q = (int)(a * sc * 8.f + 0.5f);          // 8..16
  if (q >= 16) { q = 8; ++e; if (e > 8) return s | 0x7E; }
  return s | (u8)(((e + 7) << 3) | (q - 8));
}
// ---- HW packed f32 -> fp8 (gfx950 HW fp8 = OCP e4m3fn, same as MFMA) ----
#if defined(__has_builtin)
#if __has_builtin(__builtin_amdgcn_cvt_pk_fp8_f32)
#define HAVE_CVT_FP8 1
#endif
#endif
__device__ __forceinline__ unsigned f2f8x4(float a, float b, float c, float d) {
#ifdef HAVE_CVT_FP8
  unsigned w = 0;
  w = __builtin_amdgcn_cvt_pk_fp8_f32(a, b, w, false);   // bytes 0,1
  w = __builtin_amdgcn_cvt_pk_fp8_f32(c, d, w, true);    // bytes 2,3
  return w;
#else
  return (unsigned)f2f8(a) | ((unsigned)f2f8(b) << 8) |
         ((unsigned)f2f8(c) << 16) | ((unsigned)f2f8(d) << 24);
#endif
}
__device__ __forceinline__ float f82f(u8 v) {
  unsigned s = ((unsigned)(v & 0x80u)) << 24;
  unsigned e = (v >> 3) & 0xF, m = v & 7;
  if (e == 0) {
    if (m == 0) return __uint_as_float(s);
    float f = (float)m * 0.001953125f;         // m * 2^-9
    return __uint_as_float(s | __float_as_uint(f));
  }
  return __uint_as_float(s | ((e + 120u) << 23) | (m << 20));
}
__device__ __forceinline__ void gload16(const void* g, void* lds) {
  __builtin_amdgcn_global_load_lds(
      (const __attribute__((address_space(1))) unsigned*)g,
      (__attribute__((address_space(3))) unsigned*)lds, 16, 0, 0);
}

// ----------------------------------------------------- transpose-convert ---
// in [R][C] f32 -> out [C][R] (bf16 or fp8), one 64x64 tile.
template<int OUT8>
__device__ __forceinline__ void tcvt_body(const float* __restrict__ in_,
                                          void* __restrict__ out,
                                          int R, int C, int b, int r0, int c0,
                                          size_t inb, size_t outb,
                                          u16 tile[64][65]) {
  const int t  = threadIdx.x;
  const int tr = t >> 4, tc = (t & 15) * 4;
  #pragma unroll
  for (int i = 0; i < 4; ++i) {
    int rl = i * 16 + tr;
    int r  = r0 + rl;
    if (r < R) {
      const float* in = in_ + (size_t)b * inb + (size_t)r * C + c0 + tc;
      float4 v = *(const float4*)in;
      tile[rl][tc + 0] = f2b(v.x); tile[rl][tc + 1] = f2b(v.y);
      tile[rl][tc + 2] = f2b(v.z); tile[rl][tc + 3] = f2b(v.w);
    }
  }
  __syncthreads();
  const int c  = t >> 2;
  const int rb = (t & 3) * 16;
  #pragma unroll
  for (int i = 0; i < 4; ++i) {
    int rl = rb + i * 4;
    int r  = r0 + rl;
    if (OUT8) {
      u8* orow = (u8*)out + (size_t)b * outb + (size_t)(c0 + c) * R + r0;
      if (r + 3 < R) {
        *(unsigned*)(orow + rl) =
            f2f8x4(b2f(tile[rl + 0][c]), b2f(tile[rl + 1][c]),
                   b2f(tile[rl + 2][c]), b2f(tile[rl + 3][c]));
      } else {
        for (int j = 0; j < 4; ++j)
          if (r + j < R) orow[rl + j] = f2f8(b2f(tile[rl + j][c]));
      }
    } else {
      u16* orow = (u16*)out + (size_t)b * outb + (size_t)(c0 + c) * R + r0;
      if (r + 3 < R) {
        ushort4 v;
        v.x = tile[rl + 0][c]; v.y = tile[rl + 1][c];
        v.z = tile[rl + 2][c]; v.w = tile[rl + 3][c];
        *(ushort4*)(orow + rl) = v;
      } else {
        for (int j = 0; j < 4; ++j)
          if (r + j < R) orow[rl + j] = tile[rl + j][c];
      }
    }
  }
}

// -------------------------------------------------------------- prep ------
// Small now: adj conversion + rowsum moved INTO the adj GEMM.
//  block 0        : zero the zero-page
//  block 1        : rowmap/pslot build (deterministic ranks)
//  blocks [2, +2368) : x^T fp8 tcvt;  next 64/64/128: W0^T, W1^T, outw^T.
__global__ __launch_bounds__(256) void fat_prep(
    const float* __restrict__ inputs,
    const float* __restrict__ W0w, const float* __restrict__ W1w,
    const float* __restrict__ outw,
    const int* __restrict__ ps, const int* __restrict__ hs,
    const int* __restrict__ ts,
    u8* __restrict__ xt8, u16* __restrict__ w0t, u16* __restrict__ w1t,
    u16* __restrict__ owt, int* __restrict__ rowmap, int* __restrict__ pslot,
    u16* __restrict__ zp) {
  __shared__ u16 tile[64][65];
  __shared__ int sps[PAIRS];
  const int bx = blockIdx.x;
  const int t  = threadIdx.x;

  if (bx == 0) {                              // ---- zero page
    zp[t] = 0; zp[256 + t] = 0;
  } else if (bx == 1) {                       // ---- rowmap / pslot
    sps[t] = ps[t]; sps[256 + t] = ps[256 + t];
    for (int i = t; i < MG; i += 256) rowmap[i] = 0;
    __syncthreads();
    for (int u = t; u < B_ * SENT; u += 256)
      rowmap[(u / SENT) * SLOTB + (u % SENT)] = u % SENT;
    for (int p = t; p < PAIRS; p += 256) {
      const int b = sps[p];
      int rank = 0;
      for (int q = 0; q < p; ++q) rank += (sps[q] == b) ? 1 : 0;
      const int h = hs[p], tt = ts[p];
      const int s0 = b * SLOTB + SENT + 4 * rank;
      rowmap[s0 + 0] = (h + 1) * SENT + tt;
      rowmap[s0 + 1] = (h + 1) * SENT + tt + 1;
      rowmap[s0 + 2] = (h + 2) * SENT + tt;
      rowmap[s0 + 3] = (h + 2) * SENT + tt + 1;
      pslot[p] = s0;
    }
  } else {                                    // ---- tcvt region
    int r = bx - 2;
    if (r < 2368) {                           // x^T fp8: 296 tiles x 8 batches
      const int b = r / 296, rem = r % 296;
      const int rx = rem % 37, ry = rem / 37;
      tcvt_body<1>(inputs, xt8, NP, D_, b, rx * 64, ry * 64,
                   (size_t)NP * D_, (size_t)D_ * NP, tile);
    } else if ((r -= 2368) < 64) {            // W0^T bf16
      tcvt_body<0>(W0w, w0t, 512, 512, 0, (r % 8) * 64, (r / 8) * 64,
                   0, 0, tile);
    } else if ((r -= 64) < 64) {              // W1^T bf16
      tcvt_body<0>(W1w, w1t, 512, 512, 0, (r % 8) * 64, (r / 8) * 64,
                   0, 0, tile);
    } else {                                  // outw^T bf16 (1024x512)
      r -= 64;
      tcvt_body<0>(outw, owt, 1024, 512, 0, (r % 16) * 64, (r / 16) * 64,
                   0, 0, tile);
    }
  }
}

// ------------------------------------------- 4-wave 128x128 GEMM core ------
// R13 schedule skeleton. MODE 0: A = adj **f32**, reg-staged + in-kernel
// cvt_pk->fp8 ds_write into the SAME swizzled LDS layout (frag path
// unchanged); n0==0 blocks fuse the rowsum -> rdenom (overlap rows masked
// for determinism). B = xt8/g0t8 fp8 via global_load_lds. MODE 1/2 bf16
// unchanged. MODE 1 GATHER gathers rdenom via rowmap.
template<int MODE, int WRITE_T, int GATHER>
__global__ __launch_bounds__(256, 2) void gemm8(
    const void* __restrict__ A, const void* __restrict__ A2,
    const void* __restrict__ Bm, const u16* __restrict__ Xt,
    const float* __restrict__ bias, float* __restrict__ rdenom,
    const int* __restrict__ rowmap,
    const u16* __restrict__ zp, u16* __restrict__ out, u8* __restrict__ outT,
    float ascale)
{
  constexpr bool F8   = (MODE == 0);
  constexpr int KACT   = (MODE == 0) ? NP : (MODE == 1 ? 512 : 1024);
  constexpr int KTILES = (KACT + 63) / 64;     // 37 / 8 / 16
  constexpr int EPC    = F8 ? 16 : 8;          // elements per 16B chunk
  constexpr int CPT    = F8 ? 4 : 8;           // chunks per row per K-tile
  constexpr int ABYTES = F8 ? 8192 : 16384;    // bytes per dbuf per operand

  int m0, n0, bat = 0;
  const float* Af = (const float*)A;           // MODE 0: adj f32 (per batch)
  const u8* Bb = (const u8*)Bm;
  size_t outBase = 0;
  bool ovl = false;
  if constexpr (GATHER) {
    // grid 160 = 8 XCDs x 20; 40 m-tiles (5/batch) x 4 n-tiles
    const int bx  = blockIdx.x;
    const int rid = (bx & 7) * 20 + (bx >> 3);
    const int mt  = rid >> 2;                 // 0..39
    n0 = (rid & 3) << 7;
    m0 = mt * 128;                            // slot-space
    bat = mt / 5;
    if constexpr (MODE == 0) {
      Af = (const float*)A + (size_t)bat * NP * NP;     // adj f32
      Bb = (const u8*)Bm + (size_t)bat * 512 * NP;      // g0t8
    }
  } else if constexpr (MODE == 0) {
    // grid 608 = 8 XCD chunks x 76 (one batch per chunk); 19 m x 4 n
    const int bx  = blockIdx.x;
    bat = bx & 7;
    const int loc = bx >> 3;                  // 0..75
    const int mt  = loc >> 2;                 // 0..18
    n0 = (loc & 3) << 7;
    m0 = (mt < 18) ? mt * 128 : NP - 128;     // overlap last tile
    ovl = (mt == 18);
    Af = (const float*)A + (size_t)bat * NP * NP;
    Bb = (const u8*)Bm + (size_t)bat * 512 * NP;
    outBase = (size_t)bat * NP * 512;
  } else {
    // grid 588 = 147 m x 4 n; bijective XCD chunking (q=73, r=4)
    const int bx  = blockIdx.x;
    const int xcd = bx & 7, pos = bx >> 3;
    const int rid = (xcd < 4) ? xcd * 74 + pos : 296 + (xcd - 4) * 73 + pos;
    const int mt  = rid >> 2;                 // 0..146
    n0 = (rid & 3) << 7;
    m0 = mt * 128;                            // exact (147*128 = 18816)
  }

  __shared__ __align__(16) u8 As[2 * ABYTES];
  __shared__ __align__(16) u8 Bs[2 * ABYTES];

  const int tid = threadIdx.x;
  const int l  = tid & 63;
  const int w  = tid >> 6;
  const int wm = w >> 1, wn = w & 1;
  const int lr = l & 15, lq = l >> 4;

  f32x4 acc[4][4];
  #pragma unroll
  for (int i = 0; i < 4; ++i)
    #pragma unroll
    for (int j = 0; j < 4; ++j)
      acc[i][j] = (f32x4){0.f, 0.f, 0.f, 0.f};

  int rsrc[2];
  #pragma unroll
  for (int j = 0; j < 2; ++j) {
    const int row = j * 64 + (tid >> 2);
    if constexpr (GATHER && MODE != 1) rsrc[j] = rowmap[m0 + row];
    else                               rsrc[j] = m0 + row;
  }

  // ---- MODE 0: A reg-stage (f32 loads) + convert + LDS write -------------
  float4 ar[8];
  float rsum0 = 0.f, rsum1 = 0.f;
  auto A_LOAD = [&](int kt) {                  // 8 independent float4 loads
    #pragma unroll
    for (int j = 0; j < 2; ++j) {
      const int cl   = j * 256 + tid;
      const int row  = (cl >> 2) & 127;
      const int slot = cl & 3;
      const int gch  = kt * 4 + (slot ^ ((row >> 1) & 3));
      const float* src = Af + (size_t)rsrc[j] * NP + gch * 16;
      if (gch * 16 + 16 > NP) src = (const float*)zp;
      #pragma unroll
      for (int q = 0; q < 4; ++q) ar[j * 4 + q] = *(const float4*)(src + q * 4);
    }
  };
  auto A_WRITE = [&](int d) {                  // cvt_pk + ds_write_b128
    #pragma unroll
    for (int j = 0; j < 2; ++j) {
      const int cl = j * 256 + tid;
      uint4 pk;
      pk.x = f2f8x4(ar[j*4+0].x, ar[j*4+0].y, ar[j*4+0].z, ar[j*4+0].w);
      pk.y = f2f8x4(ar[j*4+1].x, ar[j*4+1].y, ar[j*4+1].z, ar[j*4+1].w);
      pk.z = f2f8x4(ar[j*4+2].x, ar[j*4+2].y, ar[j*4+2].z, ar[j*4+2].w);
      pk.w = f2f8x4(ar[j*4+3].x, ar[j*4+3].y, ar[j*4+3].z, ar[j*4+3].w);
      *(uint4*)(As + d * ABYTES + cl * 16) = pk;
      if constexpr (MODE == 0 && !GATHER) {
        float s = (ar[j*4+0].x + ar[j*4+0].y) + (ar[j*4+0].z + ar[j*4+0].w)
                + (ar[j*4+1].x + ar[j*4+1].y) + (ar[j*4+1].z + ar[j*4+1].w)
                + (ar[j*4+2].x + ar[j*4+2].y) + (ar[j*4+2].z + ar[j*4+2].w)
                + (ar[j*4+3].x + ar[j*4+3].y) + (ar[j*4+3].z + ar[j*4+3].w);
        if (j == 0) rsum0 += s; else rsum1 += s;
      }
    }
  };
  auto STAGE_B = [&](int d, int kt) {
    #pragma unroll
    for (int j = 0; j < 2; ++j) {
      const int cl   = j * 256 + tid;
      const int row  = (cl >> 2) & 127;
      const int slot = cl & 3;
      const int gch  = kt * 4 + (slot ^ ((row >> 1) & 3));
      const u8* src  = Bb + (size_t)(n0 + row) * NP + (size_t)gch * 16;
      if (gch * 16 + 16 > KACT) src = (const u8*)zp;
      gload16(src, Bs + d * ABYTES + cl * 16);
    }
  };
  auto STAGE_BF16 = [&](int isA, int d, int kt) {   // MODE 1/2 (unchanged)
    #pragma unroll
    for (int j = 0; j < 4; ++j) {
      const int cl   = j * 256 + tid;
      const int row  = (cl >> 2) & 127;
      const int slot = cl & 3;
      const int s    = cl >> 9;
      const int gch  = kt * 8 + s * 4 + (slot ^ ((row >> 1) & 3));
      const u8* src;
      if (isA) {
        if constexpr (MODE == 2) {
          int rg = (GATHER ? rsrc[j & 1] : (m0 + row));
          src = (gch < 64)
              ? (const u8*)A  + (((size_t)(GATHER ? bat * NP : 0) + rg) * 512
                                 + (size_t)gch * 8) * 2
              : (const u8*)A2 + ((size_t)(m0 + row) * 512
                                 + (size_t)(gch - 64) * 8) * 2;
        } else {
          src = (const u8*)A + ((size_t)(m0 + row) * 512 + (size_t)gch * 8) * 2;
        }
        if (gch * EPC + EPC > KACT) src = (const u8*)zp;
        gload16(src, As + d * ABYTES + cl * 16);
      } else {
        src = (const u8*)Bm + ((size_t)(n0 + row) * KACT + (size_t)gch * 8) * 2;
        if (gch * EPC + EPC > KACT) src = (const u8*)zp;
        gload16(src, Bs + d * ABYTES + cl * 16);
      }
    }
  };

  // ------------------------------- prologue -------------------------------
  if constexpr (F8) {
    A_LOAD(0);
    STAGE_B(0, 0);
    asm volatile("s_waitcnt vmcnt(0)" ::: "memory");
    A_WRITE(0);
    asm volatile("s_waitcnt lgkmcnt(0)" ::: "memory");
  } else {
    STAGE_BF16(1, 0, 0);
    STAGE_BF16(0, 0, 0);
    asm volatile("s_waitcnt vmcnt(0)" ::: "memory");
  }
  __builtin_amdgcn_s_barrier();

  int d = 0;
  for (int kt = 0; kt < KTILES; ++kt) {
    const bool more = (kt + 1 < KTILES);
    if constexpr (F8) {
      if (more) { A_LOAD(kt + 1); STAGE_B(d ^ 1, kt + 1); }
    } else {
      if (more) { STAGE_BF16(1, d ^ 1, kt + 1); STAGE_BF16(0, d ^ 1, kt + 1); }
    }
    const u8* Ad = As + d * ABYTES;
    const u8* Bd = Bs + d * ABYTES;
    if constexpr (F8) {
      long a0[4], b0[4], a1[4], b1[4];
      #pragma unroll
      for (int f = 0; f < 4; ++f) {
        const int ra = wm * 64 + f * 16 + lr;
        const int rb = wn * 64 + f * 16 + lr;
        const int swa = (ra >> 1) & 3, swb = (rb >> 1) & 3;
        const int co = (lq >> 1), bo = (lq & 1) << 3;
        a0[f] = *(const long*)(Ad + ra * 64 + (((0 + co) ^ swa) << 4) + bo);
        b0[f] = *(const long*)(Bd + rb * 64 + (((0 + co) ^ swb) << 4) + bo);
        a1[f] = *(const long*)(Ad + ra * 64 + (((2 + co) ^ swa) << 4) + bo);
        b1[f] = *(const long*)(Bd + rb * 64 + (((2 + co) ^ swb) << 4) + bo);
      }
      asm volatile("s_waitcnt lgkmcnt(0)" ::: "memory");
      __builtin_amdgcn_sched_barrier(0);
      __builtin_amdgcn_s_setprio(1);
      #pragma unroll
      for (int mf = 0; mf < 4; ++mf)
        #pragma unroll
        for (int nf = 0; nf < 4; ++nf)
          acc[mf][nf] = __builtin_amdgcn_mfma_f32_16x16x32_fp8_fp8(
              a0[mf], b0[nf], acc[mf][nf], 0, 0, 0);
      #pragma unroll
      for (int mf = 0; mf < 4; ++mf)
        #pragma unroll
        for (int nf = 0; nf < 4; ++nf)
          acc[mf][nf] = __builtin_amdgcn_mfma_f32_16x16x32_fp8_fp8(
              a1[mf], b1[nf], acc[mf][nf], 0, 0, 0);
      __builtin_amdgcn_s_setprio(0);
      __builtin_amdgcn_sched_barrier(0);
      asm volatile("s_waitcnt vmcnt(0)" ::: "memory"); // A regs + B DMA landed
      if (more) {
        A_WRITE(d ^ 1);
        asm volatile("s_waitcnt lgkmcnt(0)" ::: "memory");  // drain ds_writes
      }
    } else {
      bf16x8 a0[4], b0[4], a1[4], b1[4];
      #pragma unroll
      for (int f = 0; f < 4; ++f) {
        const int ra = wm * 64 + f * 16 + lr;
        const int rb = wn * 64 + f * 16 + lr;
        const int sa = (lq ^ ((ra >> 1) & 3)) << 4;
        const int sb = (lq ^ ((rb >> 1) & 3)) << 4;
        a0[f] = *(const bf16x8*)(Ad + ra * 64 + sa);
        b0[f] = *(const bf16x8*)(Bd + rb * 64 + sb);
        a1[f] = *(const bf16x8*)(Ad + 8192 + ra * 64 + sa);
        b1[f] = *(const bf16x8*)(Bd + 8192 + rb * 64 + sb);
      }
      asm volatile("s_waitcnt lgkmcnt(0)" ::: "memory");
      __builtin_amdgcn_sched_barrier(0);
      __builtin_amdgcn_s_setprio(1);
      #pragma unroll
      for (int mf = 0; mf < 4; ++mf)
        #pragma unroll
        for (int nf = 0; nf < 4; ++nf)
          acc[mf][nf] = __builtin_amdgcn_mfma_f32_16x16x32_bf16(
              a0[mf], b0[nf], acc[mf][nf], 0, 0, 0);
      #pragma unroll
      for (int mf = 0; mf < 4; ++mf)
        #pragma unroll
        for (int nf = 0; nf < 4; ++nf)
          acc[mf][nf] = __builtin_amdgcn_mfma_f32_16x16x32_bf16(
              a1[mf], b1[nf], acc[mf][nf], 0, 0, 0);
      __builtin_amdgcn_s_setprio(0);
      __builtin_amdgcn_sched_barrier(0);
      asm volatile("s_waitcnt vmcnt(0)" ::: "memory");
    }
    __builtin_amdgcn_s_barrier();
    d ^= 1;
  }

  // ---- fused rowsum -> rdenom (MODE 0 non-gather, n0==0 blocks only) -----
  if constexpr (MODE == 0 && !GATHER) {
    if (n0 == 0) {
      #pragma unroll
      for (int j = 0; j < 2; ++j) {
        float s = (j == 0) ? rsum0 : rsum1;
        s += __shfl_xor(s, 1, 64);
        s += __shfl_xor(s, 2, 64);
        const int lrow = j * 64 + (tid >> 2);      // 0..127
        if ((l & 3) == 0 && (!ovl || m0 + lrow >= 2304))
          rdenom[(size_t)bat * NP + m0 + lrow] = 1.f / (s + 1.f);
      }
    }
  }

  // --------------------------------------------------------- epilogue ----
  #pragma unroll
  for (int mf = 0; mf < 4; ++mf) {
    const int gm0 = m0 + wm * 64 + mf * 16 + lq * 4;
    f32x4 rd;
    if constexpr (MODE == 1) {
      if constexpr (GATHER) {
        #pragma unroll
        for (int r = 0; r < 4; ++r)
          rd[r] = rdenom[(size_t)bat * NP + rowmap[gm0 + r]];
      } else {
        rd = *(const f32x4*)(rdenom + gm0);
      }
    }
    int rsm[4];
    if constexpr (GATHER && MODE == 0) {
      #pragma unroll
      for (int r = 0; r < 4; ++r) rsm[r] = rowmap[gm0 + r];
    }
    #pragma unroll
    for (int nf = 0; nf < 4; ++nf) {
      const int gn = n0 + wn * 64 + nf * 16 + lr;
      float vf[4];
      if constexpr (MODE == 0) {
        float xf[4];
        if constexpr (GATHER) {
          #pragma unroll
          for (int r = 0; r < 4; ++r)
            xf[r] = b2f(Xt[((size_t)bat * NP + rsm[r]) * 512 + gn]);
        } else {
          uchar4 xv = *(const uchar4*)(Bb + (size_t)gn * NP + gm0);
          xf[0] = f82f(xv.x); xf[1] = f82f(xv.y);
          xf[2] = f82f(xv.z); xf[3] = f82f(xv.w);
        }
        #pragma unroll
        for (int r = 0; r < 4; ++r) vf[r] = acc[mf][nf][r] * ascale + xf[r];
      } else if constexpr (MODE == 1) {
        const float bn = 2.f * bias[gn];
        #pragma unroll
        for (int r = 0; r < 4; ++r)
          vf[r] = fmaxf((acc[mf][nf][r] + bn) * rd[r], 0.f);
      } else {
        const float bn = bias[gn];
        #pragma unroll
        for (int r = 0; r < 4; ++r) vf[r] = acc[mf][nf][r] + bn;
      }
      #pragma unroll
      for (int r = 0; r < 4; ++r)
        out[outBase + (size_t)(gm0 + r) * 512 + gn] = f2b(vf[r]);
      if constexpr (WRITE_T) {
        const int bb = gm0 / NP;               // quad never straddles batch
        const int ml = gm0 - bb * NP;
        *(unsigned*)(outT + ((size_t)bb * 512 + gn) * NP + ml) =
            f2f8x4(vf[0] * GSCALE, vf[1] * GSCALE,
                   vf[2] * GSCALE, vf[3] * GSCALE);
      }
    }
  }
}

// ----------------------------------------------------------- fused heads ---
__global__ __launch_bounds__(256) void heads_kernel(
    const float* __restrict__ ner, const u16* __restrict__ logits_g,
    const float* __restrict__ nw, const float* __restrict__ nb,
    const float* __restrict__ refeat, const float* __restrict__ rw,
    const float* __restrict__ rb, const int* __restrict__ pslot,
    float* __restrict__ outp) {
  __shared__ float avg[D_];
  if (blockIdx.x < 96) {
    const int r = blockIdx.x * 4 + (threadIdx.x >> 6);   // 0..383
    const int b = r / SENT, tp = r % SENT;
    const int lane = threadIdx.x & 63;
    const float* nrow = ner      + ((size_t)b * SENT  + tp) * D_;
    const u16*   lrow = logits_g + ((size_t)b * SLOTB + tp) * D_;
    float rv[16];
    #pragma unroll
    for (int i = 0; i < 8; ++i) rv[i]     = nrow[lane + i * 64];
    #pragma unroll
    for (int i = 0; i < 8; ++i) rv[8 + i] = b2f(lrow[lane + i * 64]);
    for (int j = 0; j < NERL; ++j) {
      float s = 0.f;
      #pragma unroll
      for (int i = 0; i < 16; ++i)
        s = fmaf(rv[i], nw[(size_t)(lane + i * 64) * NERL + j], s);
      for (int o = 32; o > 0; o >>= 1) s += __shfl_down(s, o);
      if (lane == 0) outp[r * NERL + j] = s + nb[j];
    }
  } else {
    const int p = blockIdx.x - 96;
    const u16* r0 = logits_g + (size_t)pslot[p] * D_;   // 4 consecutive slots
    for (int dd = threadIdx.x; dd < D_; dd += 256)
      avg[dd] = 0.25f * (b2f(r0[dd]) + b2f(r0[D_ + dd]) +
                         b2f(r0[2 * D_ + dd]) + b2f(r0[3 * D_ + dd]));
    __syncthreads();
    const int wave = threadIdx.x >> 6, lane = threadIdx.x & 63;
    const float* rf = refeat + (size_t)p * D_;
    float* out = outp + B_ * SENT * NERL;
    for (int jj = 0; jj < 8; ++jj) {
      int j = wave * 8 + jj;
      float s = 0.f;
      #pragma unroll
      for (int i = 0; i < 8; ++i) {
        int k = lane + i * 64;
        s = fmaf(rf[k],  rw[(size_t)k * REL + j], s);
        s = fmaf(avg[k], rw[(size_t)(k + D_) * REL + j], s);
      }
      for (int o = 32; o > 0; o >>= 1) s += __shfl_down(s, o);
      if (lane == 0) out[p * REL + j] = s + rb[j];
    }
  }
}

// --------------------------------------------------------------- launch ----
extern "C" void kernel_launch(void* const* d_in, const int* in_sizes, int n_in,
                              void* d_out, int out_size, void* d_ws, size_t ws_size,
                              hipStream_t stream) {
  const float* inputs = (const float*)d_in[0];
  const float* ner    = (const float*)d_in[1];
  const float* refeat = (const float*)d_in[2];
  const float* adj    = (const float*)d_in[3];
  const float* W0w    = (const float*)d_in[4];
  const float* W0b    = (const float*)d_in[5];
  const float* W1w    = (const float*)d_in[6];
  const float* W1b    = (const float*)d_in[7];
  const float* outw   = (const float*)d_in[8];
  const float* outb   = (const float*)d_in[9];
  const float* nerw   = (const float*)d_in[10];
  const float* nerb   = (const float*)d_in[11];
  const float* rew    = (const float*)d_in[12];
  const float* reb    = (const float*)d_in[13];
  const int*   ps     = (const int*)d_in[14];
  const int*   hs     = (const int*)d_in[15];
  const int*   ts     = (const int*)d_in[16];
  (void)in_sizes; (void)n_in; (void)out_size; (void)ws_size;
  float* outp = (float*)d_out;

  char* ws = (char*)d_ws;
  size_t off = 0;
  float* rdenom = (float*)(ws + off); off += (size_t)MTOT * 4;
  u16* zp  = (u16*)(ws + off); off += 1024;
  u16* w0t = (u16*)(ws + off); off += 512 * 512 * 2;
  u16* w1t = (u16*)(ws + off); off += 512 * 512 * 2;
  u16* owt = (u16*)(ws + off); off += 512 * 1024 * 2;
  u8*  xt8 = (u8*)(ws + off); off += (size_t)B_ * 512 * NP;       // x^T8 / g0^T8
  u16* S   = (u16*)(ws + off); off += (size_t)MTOT * 512 * 2;
  u16* g0  = (u16*)(ws + off); off += (size_t)MTOT * 512 * 2;
  int* rowmap = (int*)(ws + off); off += (size_t)MG * 4;
  int* pslot  = (int*)(ws + off); off += (size_t)PAIRS * 4;
  u16* S_g      = (u16*)(ws + off); off += (size_t)MG * 512 * 2;
  u16* g1_g     = (u16*)(ws + off); off += (size_t)MG * 512 * 2;
  u16* logits_g = (u16*)(ws + off); off += (size_t)MG * 512 * 2;

  // small prep: zp, rowmap/pslot, x^T fp8 + weight transposes
  const int FATG = 2 + 2368 + 64 + 64 + 128;   // 2626
  fat_prep<<<FATG, 256, 0, stream>>>(inputs, W0w, W1w, outw, ps, hs, ts,
                                     xt8, w0t, w1t, owt, rowmap, pslot, zp);

  // Layer 1: S = adj@x + x (adj f32 converted in-kernel; rowsum fused);
  //          g0 = relu((S@W0+2b)/denom) (+ g0^T fp8*32)
  gemm8<0,0,0><<<608, 256, 0, stream>>>(adj, nullptr, xt8, nullptr,
                                        nullptr, rdenom, nullptr, zp, S,
                                        nullptr, 1.0f);
  gemm8<1,1,0><<<588, 256, 0, stream>>>(S, nullptr, w0t, nullptr,
                                        W0b, rdenom, nullptr, zp, g0,
                                        xt8, 1.0f);
  // Layer 2 (gathered, M = 5120 slots)
  gemm8<0,0,1><<<160, 256, 0, stream>>>(adj, nullptr, xt8, g0,
                                        nullptr, rdenom, rowmap, zp, S_g,
                                        nullptr, 1.0f / GSCALE);
  gemm8<1,0,1><<<160, 256, 0, stream>>>(S_g, nullptr, w1t, nullptr,
                                        W1b, rdenom, rowmap, zp, g1_g,
                                        nullptr, 1.0f);
  gemm8<2,0,1><<<160, 256, 0, stream>>>(g0, g1_g, owt, nullptr,
                                        outb, rdenom, rowmap, zp, logits_g,
                                        nullptr, 1.0f);

  heads_kernel<<<608, 256, 0, stream>>>(ner, logits_g, nerw, nerb,
                                        refeat, rew, reb, pslot, outp);
}

// Round 18
// 286.222 us; speedup vs baseline: 1.2944x; 1.2944x over previous
//
#include <hip/hip_runtime.h>
#include <hip/hip_bf16.h>

#define B_    8
#define NP    2352
#define D_    512
#define SENT  48
#define PAIRS 512
#define NERL  16
#define REL   32
#define MTOT  (B_*NP)   // 18816
#define SLOTB 640       // slots per batch (48 ner + up to 148 pairs * 4)
#define MG    (B_*SLOTB) // 5120 gathered slots = 40 tiles of 128
#define GSCALE 32.0f    // g0 -> fp8 pre-scale (avoids e4m3 denormal region)

typedef unsigned short u16;
typedef unsigned char  u8;
typedef __bf16 bf16x8 __attribute__((ext_vector_type(8)));
typedef float  f32x4  __attribute__((ext_vector_type(4)));

__device__ __forceinline__ u16 f2b(float f) {
  union { float f; unsigned u; } c; c.f = f;
  unsigned u = c.u;
  u += 0x7fffu + ((u >> 16) & 1u);           // round-to-nearest-even
  return (u16)(u >> 16);
}
__device__ __forceinline__ float b2f(u16 h) {
  union { unsigned u; float f; } c; c.u = ((unsigned)h) << 16;
  return c.f;
}
// ---- e4m3fn encode (soft fallback) ----
__device__ __forceinline__ u8 f2f8(float f) {
  unsigned u = __float_as_uint(f);
  u8 s = (u >> 24) & 0x80;
  float a = fabsf(f);
  if (a < 0.0009765625f) return s;            // < 2^-10 -> 0
  if (a >= 448.f) return s | 0x7E;            // clamp to max finite 448
  int e = ((u >> 23) & 0xFF) - 127;
  if (e < -6) {                               // denormal: m * 2^-9
    int q = (int)(a * 512.f + 0.5f);
    if (q >= 8) return s | 0x08;
    return s | (u8)q;
  }
  float sc = __uint_as_float((unsigned)((127 - e) << 23));   // 2^-e
  int q = (int)(a * sc * 8.f + 0.5f);          // 8..16
  if (q >= 16) { q = 8; ++e; if (e > 8) return s | 0x7E; }
  return s | (u8)(((e + 7) << 3) | (q - 8));
}
// ---- HW packed f32 -> fp8 (gfx950 HW fp8 = OCP e4m3fn, same as MFMA) ----
#if defined(__has_builtin)
#if __has_builtin(__builtin_amdgcn_cvt_pk_fp8_f32)
#define HAVE_CVT_FP8 1
#endif
#endif
__device__ __forceinline__ unsigned f2f8x4(float a, float b, float c, float d) {
#ifdef HAVE_CVT_FP8
  unsigned w = 0;
  w = __builtin_amdgcn_cvt_pk_fp8_f32(a, b, w, false);   // bytes 0,1
  w = __builtin_amdgcn_cvt_pk_fp8_f32(c, d, w, true);    // bytes 2,3
  return w;
#else
  return (unsigned)f2f8(a) | ((unsigned)f2f8(b) << 8) |
         ((unsigned)f2f8(c) << 16) | ((unsigned)f2f8(d) << 24);
#endif
}
__device__ __forceinline__ float f82f(u8 v) {
  unsigned s = ((unsigned)(v & 0x80u)) << 24;
  unsigned e = (v >> 3) & 0xF, m = v & 7;
  if (e == 0) {
    if (m == 0) return __uint_as_float(s);
    float f = (float)m * 0.001953125f;         // m * 2^-9
    return __uint_as_float(s | __float_as_uint(f));
  }
  return __uint_as_float(s | ((e + 120u) << 23) | (m << 20));
}
__device__ __forceinline__ void gload16(const void* g, void* lds) {
  __builtin_amdgcn_global_load_lds(
      (const __attribute__((address_space(1))) unsigned*)g,
      (__attribute__((address_space(3))) unsigned*)lds, 16, 0, 0);
}

// ----------------------------------------------------- transpose-convert ---
// in [R][C] f32 -> out [C][R] (bf16 or fp8), one 64x64 tile.
template<int OUT8>
__device__ __forceinline__ void tcvt_body(const float* __restrict__ in_,
                                          void* __restrict__ out,
                                          int R, int C, int b, int r0, int c0,
                                          size_t inb, size_t outb,
                                          u16 tile[64][65]) {
  const int t  = threadIdx.x;
  const int tr = t >> 4, tc = (t & 15) * 4;
  #pragma unroll
  for (int i = 0; i < 4; ++i) {
    int rl = i * 16 + tr;
    int r  = r0 + rl;
    if (r < R) {
      const float* in = in_ + (size_t)b * inb + (size_t)r * C + c0 + tc;
      float4 v = *(const float4*)in;
      tile[rl][tc + 0] = f2b(v.x); tile[rl][tc + 1] = f2b(v.y);
      tile[rl][tc + 2] = f2b(v.z); tile[rl][tc + 3] = f2b(v.w);
    }
  }
  __syncthreads();
  const int c  = t >> 2;
  const int rb = (t & 3) * 16;
  #pragma unroll
  for (int i = 0; i < 4; ++i) {
    int rl = rb + i * 4;
    int r  = r0 + rl;
    if (OUT8) {
      u8* orow = (u8*)out + (size_t)b * outb + (size_t)(c0 + c) * R + r0;
      if (r + 3 < R) {
        *(unsigned*)(orow + rl) =
            f2f8x4(b2f(tile[rl + 0][c]), b2f(tile[rl + 1][c]),
                   b2f(tile[rl + 2][c]), b2f(tile[rl + 3][c]));
      } else {
        for (int j = 0; j < 4; ++j)
          if (r + j < R) orow[rl + j] = f2f8(b2f(tile[rl + j][c]));
      }
    } else {
      u16* orow = (u16*)out + (size_t)b * outb + (size_t)(c0 + c) * R + r0;
      if (r + 3 < R) {
        ushort4 v;
        v.x = tile[rl + 0][c]; v.y = tile[rl + 1][c];
        v.z = tile[rl + 2][c]; v.w = tile[rl + 3][c];
        *(ushort4*)(orow + rl) = v;
      } else {
        for (int j = 0; j < 4; ++j)
          if (r + j < R) orow[rl + j] = tile[rl + j][c];
      }
    }
  }
}

// -------------------------------------------------------------- fat prep ---
//  blocks [0, 4704)  : adj f32 -> fp8 + rowsum. Wave-per-row, 4 rows/block.
//                      Each lane owns 4 consecutive 16B chunks: 64B f32
//                      read + ONE uint4 (16B) store  (store-width A/B).
//  block  4704       : zero page;  4705: rowmap/pslot
//  blocks [4706,...) : x^T fp8 tcvt; then W0^T, W1^T, outw^T.
#define ADJB (MTOT / 4)   // 4704
__global__ __launch_bounds__(256) void fat_prep(
    const float* __restrict__ adj, const float* __restrict__ inputs,
    const float* __restrict__ W0w, const float* __restrict__ W1w,
    const float* __restrict__ outw,
    const int* __restrict__ ps, const int* __restrict__ hs,
    const int* __restrict__ ts,
    u8* __restrict__ adj8, float* __restrict__ rdenom,
    u8* __restrict__ xt8, u16* __restrict__ w0t, u16* __restrict__ w1t,
    u16* __restrict__ owt, int* __restrict__ rowmap, int* __restrict__ pslot,
    u16* __restrict__ zp) {
  __shared__ u16 tile[64][65];
  __shared__ int sps[PAIRS];
  const int bx = blockIdx.x;
  const int t  = threadIdx.x;

  if (bx < ADJB) {                            // ---- adj rows, wave-per-row
    const int row  = bx * 4 + (t >> 6);       // 0..18815
    const int lane = t & 63;
    const float4* src = (const float4*)(adj + (size_t)row * NP);
    uint4* dst = (uint4*)(adj8 + (size_t)row * NP);   // 147 uint4 per row
    // groups g = lane, lane+64 (full) and lane+128 for lanes 0..18
    float4 v[8];
    #pragma unroll
    for (int j = 0; j < 2; ++j)
      #pragma unroll
      for (int q = 0; q < 4; ++q)
        v[j * 4 + q] = src[(lane + j * 64) * 4 + q];   // independent loads
    const bool extra = lane < (147 - 128);             // lanes 0..18
    float4 e[4];
    if (extra)
      #pragma unroll
      for (int q = 0; q < 4; ++q) e[q] = src[(lane + 128) * 4 + q];
    float s = 0.f;
    #pragma unroll
    for (int j = 0; j < 2; ++j) {
      uint4 pk;
      pk.x = f2f8x4(v[j*4+0].x, v[j*4+0].y, v[j*4+0].z, v[j*4+0].w);
      pk.y = f2f8x4(v[j*4+1].x, v[j*4+1].y, v[j*4+1].z, v[j*4+1].w);
      pk.z = f2f8x4(v[j*4+2].x, v[j*4+2].y, v[j*4+2].z, v[j*4+2].w);
      pk.w = f2f8x4(v[j*4+3].x, v[j*4+3].y, v[j*4+3].z, v[j*4+3].w);
      dst[lane + j * 64] = pk;
      #pragma unroll
      for (int q = 0; q < 4; ++q)
        s += (v[j*4+q].x + v[j*4+q].y) + (v[j*4+q].z + v[j*4+q].w);
    }
    if (extra) {
      uint4 pk;
      pk.x = f2f8x4(e[0].x, e[0].y, e[0].z, e[0].w);
      pk.y = f2f8x4(e[1].x, e[1].y, e[1].z, e[1].w);
      pk.z = f2f8x4(e[2].x, e[2].y, e[2].z, e[2].w);
      pk.w = f2f8x4(e[3].x, e[3].y, e[3].z, e[3].w);
      dst[lane + 128] = pk;
      #pragma unroll
      for (int q = 0; q < 4; ++q)
        s += (e[q].x + e[q].y) + (e[q].z + e[q].w);
    }
    #pragma unroll
    for (int o = 32; o > 0; o >>= 1) s += __shfl_down(s, o, 64);
    if (lane == 0) rdenom[row] = 1.f / (s + 1.f);
  } else if (bx == ADJB) {                    // ---- zero page
    zp[t] = 0; zp[256 + t] = 0;
  } else if (bx == ADJB + 1) {                // ---- rowmap / pslot
    sps[t] = ps[t]; sps[256 + t] = ps[256 + t];
    for (int i = t; i < MG; i += 256) rowmap[i] = 0;
    __syncthreads();
    for (int u = t; u < B_ * SENT; u += 256)
      rowmap[(u / SENT) * SLOTB + (u % SENT)] = u % SENT;
    for (int p = t; p < PAIRS; p += 256) {
      const int b = sps[p];
      int rank = 0;
      for (int q = 0; q < p; ++q) rank += (sps[q] == b) ? 1 : 0;
      const int h = hs[p], tt = ts[p];
      const int s0 = b * SLOTB + SENT + 4 * rank;
      rowmap[s0 + 0] = (h + 1) * SENT + tt;
      rowmap[s0 + 1] = (h + 1) * SENT + tt + 1;
      rowmap[s0 + 2] = (h + 2) * SENT + tt;
      rowmap[s0 + 3] = (h + 2) * SENT + tt + 1;
      pslot[p] = s0;
    }
  } else {                                    // ---- tcvt region
    int r = bx - (ADJB + 2);
    if (r < 2368) {                           // x^T fp8: 296 tiles x 8 batches
      const int b = r / 296, rem = r % 296;
      const int rx = rem % 37, ry = rem / 37;
      tcvt_body<1>(inputs, xt8, NP, D_, b, rx * 64, ry * 64,
                   (size_t)NP * D_, (size_t)D_ * NP, tile);
    } else if ((r -= 2368) < 64) {            // W0^T bf16
      tcvt_body<0>(W0w, w0t, 512, 512, 0, (r % 8) * 64, (r / 8) * 64,
                   0, 0, tile);
    } else if ((r -= 64) < 64) {              // W1^T bf16
      tcvt_body<0>(W1w, w1t, 512, 512, 0, (r % 8) * 64, (r / 8) * 64,
                   0, 0, tile);
    } else {                                  // outw^T bf16 (1024x512)
      r -= 64;
      tcvt_body<0>(outw, owt, 1024, 512, 0, (r % 16) * 64, (r / 16) * 64,
                   0, 0, tile);
    }
  }
}

// ------------------------------------------- 4-wave 128x128 GEMM core ------
// R13 structure unchanged: BM=BN=128, BK=64, dbuf-2, T3-min schedule,
// both-sides 16B-chunk swizzle, zero-page K-tail, 2+ blocks/CU.
// MODE 0 fp8 e4m3 (A=adj8, B=x^T8/g0^T8*32); MODE 1/2 bf16.
// MODE 1 GATHER gathers rdenom directly via rowmap.
template<int MODE, int WRITE_T, int GATHER>
__global__ __launch_bounds__(256, 2) void gemm8(
    const void* __restrict__ A, const void* __restrict__ A2,
    const void* __restrict__ Bm, const u16* __restrict__ Xt,
    const float* __restrict__ bias, const float* __restrict__ rdenom,
    const int* __restrict__ rowmap,
    const u16* __restrict__ zp, u16* __restrict__ out, u8* __restrict__ outT,
    float ascale)
{
  constexpr bool F8   = (MODE == 0);
  constexpr int KACT   = (MODE == 0) ? NP : (MODE == 1 ? 512 : 1024);
  constexpr int KTILES = (KACT + 63) / 64;     // 37 / 8 / 16
  constexpr int EPC    = F8 ? 16 : 8;          // elements per 16B chunk
  constexpr int CPT    = F8 ? 4 : 8;           // chunks per row per K-tile
  constexpr int NJ     = F8 ? 2 : 4;           // stage issues per thread
  constexpr int ABYTES = F8 ? 8192 : 16384;    // bytes per dbuf per operand

  int m0, n0, bat = 0;
  const u8* Ab = (const u8*)A;
  const u8* Bb = (const u8*)Bm;
  size_t outBase = 0;
  if constexpr (GATHER) {
    // grid 160 = 8 XCDs x 20; 40 m-tiles (5/batch) x 4 n-tiles
    const int bx  = blockIdx.x;
    const int rid = (bx & 7) * 20 + (bx >> 3);
    const int mt  = rid >> 2;                 // 0..39
    n0 = (rid & 3) << 7;
    m0 = mt * 128;                            // slot-space
    bat = mt / 5;
    if constexpr (MODE == 0) {
      Ab = (const u8*)A  + (size_t)bat * NP * NP;       // adj8
      Bb = (const u8*)Bm + (size_t)bat * 512 * NP;      // g0t8
    }
  } else if constexpr (MODE == 0) {
    // grid 608 = 8 XCD chunks x 76 (one batch per chunk); 19 m x 4 n
    const int bx  = blockIdx.x;
    bat = bx & 7;
    const int loc = bx >> 3;                  // 0..75
    const int mt  = loc >> 2;                 // 0..18
    n0 = (loc & 3) << 7;
    m0 = (mt < 18) ? mt * 128 : NP - 128;     // overlap last tile
    Ab = (const u8*)A  + (size_t)bat * NP * NP;
    Bb = (const u8*)Bm + (size_t)bat * 512 * NP;
    outBase = (size_t)bat * NP * 512;
  } else {
    // grid 588 = 147 m x 4 n; bijective XCD chunking (q=73, r=4)
    const int bx  = blockIdx.x;
    const int xcd = bx & 7, pos = bx >> 3;
    const int rid = (xcd < 4) ? xcd * 74 + pos : 296 + (xcd - 4) * 73 + pos;
    const int mt  = rid >> 2;                 // 0..146
    n0 = (rid & 3) << 7;
    m0 = mt * 128;                            // exact (147*128 = 18816)
  }

  __shared__ __align__(16) u8 As[2 * ABYTES];
  __shared__ __align__(16) u8 Bs[2 * ABYTES];

  const int tid = threadIdx.x;
  const int l  = tid & 63;
  const int w  = tid >> 6;
  const int wm = w >> 1, wn = w & 1;
  const int lr = l & 15, lq = l >> 4;

  f32x4 acc[4][4];
  #pragma unroll
  for (int i = 0; i < 4; ++i)
    #pragma unroll
    for (int j = 0; j < 4; ++j)
      acc[i][j] = (f32x4){0.f, 0.f, 0.f, 0.f};

  int rsrc[2];
  #pragma unroll
  for (int j = 0; j < 2; ++j) {
    const int row = j * 64 + (tid >> 2);
    if constexpr (GATHER && MODE != 1) rsrc[j] = rowmap[m0 + row];
    else                               rsrc[j] = m0 + row;
  }

  auto STAGE = [&](int isA, int d, int kt) {
    #pragma unroll
    for (int j = 0; j < NJ; ++j) {
      const int cl   = j * 256 + tid;
      const int row  = (cl >> 2) & 127;
      const int slot = cl & 3;
      const int s    = F8 ? 0 : (cl >> 9);
      const int gch  = kt * CPT + s * 4 + (slot ^ ((row >> 1) & 3));
      const u8* src;
      if (isA) {
        if constexpr (MODE == 0) {
          src = Ab + (size_t)rsrc[j & 1] * NP + (size_t)gch * 16;
        } else if constexpr (MODE == 1) {
          src = (const u8*)A + ((size_t)(m0 + row) * 512 + (size_t)gch * 8) * 2;
        } else {   // MODE 2: concat(g0, g1) over k
          int rg = (GATHER ? rsrc[j & 1] : (m0 + row));
          src = (gch < 64)
              ? (const u8*)A  + (((size_t)(GATHER ? bat * NP : 0) + rg) * 512
                                 + (size_t)gch * 8) * 2
              : (const u8*)A2 + ((size_t)(m0 + row) * 512
                                 + (size_t)(gch - 64) * 8) * 2;
        }
        if (gch * EPC + EPC > KACT) src = (const u8*)zp;
        gload16(src, As + d * ABYTES + cl * 16);
      } else {
        if constexpr (F8)
          src = Bb + (size_t)(n0 + row) * NP + (size_t)gch * 16;
        else
          src = (const u8*)Bm + ((size_t)(n0 + row) * KACT + (size_t)gch * 8) * 2;
        if (gch * EPC + EPC > KACT) src = (const u8*)zp;
        gload16(src, Bs + d * ABYTES + cl * 16);
      }
    }
  };

  // prologue: tile 0 into buf 0
  STAGE(1, 0, 0);
  STAGE(0, 0, 0);
  asm volatile("s_waitcnt vmcnt(0)" ::: "memory");
  __builtin_amdgcn_s_barrier();

  int d = 0;
  for (int kt = 0; kt < KTILES; ++kt) {
    if (kt + 1 < KTILES) {
      STAGE(1, d ^ 1, kt + 1);
      STAGE(0, d ^ 1, kt + 1);
    }
    const u8* Ad = As + d * ABYTES;
    const u8* Bd = Bs + d * ABYTES;
    if constexpr (F8) {
      long a0[4], b0[4], a1[4], b1[4];
      #pragma unroll
      for (int f = 0; f < 4; ++f) {
        const int ra = wm * 64 + f * 16 + lr;
        const int rb = wn * 64 + f * 16 + lr;
        const int swa = (ra >> 1) & 3, swb = (rb >> 1) & 3;
        const int co = (lq >> 1), bo = (lq & 1) << 3;
        a0[f] = *(const long*)(Ad + ra * 64 + (((0 + co) ^ swa) << 4) + bo);
        b0[f] = *(const long*)(Bd + rb * 64 + (((0 + co) ^ swb) << 4) + bo);
        a1[f] = *(const long*)(Ad + ra * 64 + (((2 + co) ^ swa) << 4) + bo);
        b1[f] = *(const long*)(Bd + rb * 64 + (((2 + co) ^ swb) << 4) + bo);
      }
      asm volatile("s_waitcnt lgkmcnt(0)" ::: "memory");
      __builtin_amdgcn_sched_barrier(0);
      __builtin_amdgcn_s_setprio(1);
      #pragma unroll
      for (int mf = 0; mf < 4; ++mf)
        #pragma unroll
        for (int nf = 0; nf < 4; ++nf)
          acc[mf][nf] = __builtin_amdgcn_mfma_f32_16x16x32_fp8_fp8(
              a0[mf], b0[nf], acc[mf][nf], 0, 0, 0);
      #pragma unroll
      for (int mf = 0; mf < 4; ++mf)
        #pragma unroll
        for (int nf = 0; nf < 4; ++nf)
          acc[mf][nf] = __builtin_amdgcn_mfma_f32_16x16x32_fp8_fp8(
              a1[mf], b1[nf], acc[mf][nf], 0, 0, 0);
      __builtin_amdgcn_s_setprio(0);
      __builtin_amdgcn_sched_barrier(0);
    } else {
      bf16x8 a0[4], b0[4], a1[4], b1[4];
      #pragma unroll
      for (int f = 0; f < 4; ++f) {
        const int ra = wm * 64 + f * 16 + lr;
        const int rb = wn * 64 + f * 16 + lr;
        const int sa = (lq ^ ((ra >> 1) & 3)) << 4;
        const int sb = (lq ^ ((rb >> 1) & 3)) << 4;
        a0[f] = *(const bf16x8*)(Ad + ra * 64 + sa);
        b0[f] = *(const bf16x8*)(Bd + rb * 64 + sb);
        a1[f] = *(const bf16x8*)(Ad + 8192 + ra * 64 + sa);
        b1[f] = *(const bf16x8*)(Bd + 8192 + rb * 64 + sb);
      }
      asm volatile("s_waitcnt lgkmcnt(0)" ::: "memory");
      __builtin_amdgcn_sched_barrier(0);
      __builtin_amdgcn_s_setprio(1);
      #pragma unroll
      for (int mf = 0; mf < 4; ++mf)
        #pragma unroll
        for (int nf = 0; nf < 4; ++nf)
          acc[mf][nf] = __builtin_amdgcn_mfma_f32_16x16x32_bf16(
              a0[mf], b0[nf], acc[mf][nf], 0, 0, 0);
      #pragma unroll
      for (int mf = 0; mf < 4; ++mf)
        #pragma unroll
        for (int nf = 0; nf < 4; ++nf)
          acc[mf][nf] = __builtin_amdgcn_mfma_f32_16x16x32_bf16(
              a1[mf], b1[nf], acc[mf][nf], 0, 0, 0);
      __builtin_amdgcn_s_setprio(0);
      __builtin_amdgcn_sched_barrier(0);
    }
    asm volatile("s_waitcnt vmcnt(0)" ::: "memory");  // next tile landed
    __builtin_amdgcn_s_barrier();
    d ^= 1;
  }

  // --------------------------------------------------------- epilogue ----
  #pragma unroll
  for (int mf = 0; mf < 4; ++mf) {
    const int gm0 = m0 + wm * 64 + mf * 16 + lq * 4;
    f32x4 rd;
    if constexpr (MODE == 1) {
      if constexpr (GATHER) {
        #pragma unroll
        for (int r = 0; r < 4; ++r)
          rd[r] = rdenom[(size_t)bat * NP + rowmap[gm0 + r]];
      } else {
        rd = *(const f32x4*)(rdenom + gm0);
      }
    }
    int rsm[4];
    if constexpr (GATHER && MODE == 0) {
      #pragma unroll
      for (int r = 0; r < 4; ++r) rsm[r] = rowmap[gm0 + r];
    }
    #pragma unroll
    for (int nf = 0; nf < 4; ++nf) {
      const int gn = n0 + wn * 64 + nf * 16 + lr;
      float vf[4];
      if constexpr (MODE == 0) {
        float xf[4];
        if constexpr (GATHER) {
          #pragma unroll
          for (int r = 0; r < 4; ++r)
            xf[r] = b2f(Xt[((size_t)bat * NP + rsm[r]) * 512 + gn]);
        } else {
          uchar4 xv = *(const uchar4*)(Bb + (size_t)gn * NP + gm0);
          xf[0] = f82f(xv.x); xf[1] = f82f(xv.y);
          xf[2] = f82f(xv.z); xf[3] = f82f(xv.w);
        }
        #pragma unroll
        for (int r = 0; r < 4; ++r) vf[r] = acc[mf][nf][r] * ascale + xf[r];
      } else if constexpr (MODE == 1) {
        const float bn = 2.f * bias[gn];
        #pragma unroll
        for (int r = 0; r < 4; ++r)
          vf[r] = fmaxf((acc[mf][nf][r] + bn) * rd[r], 0.f);
      } else {
        const float bn = bias[gn];
        #pragma unroll
        for (int r = 0; r < 4; ++r) vf[r] = acc[mf][nf][r] + bn;
      }
      #pragma unroll
      for (int r = 0; r < 4; ++r)
        out[outBase + (size_t)(gm0 + r) * 512 + gn] = f2b(vf[r]);
      if constexpr (WRITE_T) {
        const int bb = gm0 / NP;               // quad never straddles batch
        const int ml = gm0 - bb * NP;
        *(unsigned*)(outT + ((size_t)bb * 512 + gn) * NP + ml) =
            f2f8x4(vf[0] * GSCALE, vf[1] * GSCALE,
                   vf[2] * GSCALE, vf[3] * GSCALE);
      }
    }
  }
}

// ----------------------------------------------------------- fused heads ---
// blocks [0,96): ner (4 rows/block, one per wave); blocks [96,608): pairs.
__global__ __launch_bounds__(256) void heads_kernel(
    const float* __restrict__ ner, const u16* __restrict__ logits_g,
    const float* __restrict__ nw, const float* __restrict__ nb,
    const float* __restrict__ refeat, const float* __restrict__ rw,
    const float* __restrict__ rb, const int* __restrict__ pslot,
    float* __restrict__ outp) {
  __shared__ float avg[D_];
  if (blockIdx.x < 96) {
    const int r = blockIdx.x * 4 + (threadIdx.x >> 6);   // 0..383
    const int b = r / SENT, tp = r % SENT;
    const int lane = threadIdx.x & 63;
    const float* nrow = ner      + ((size_t)b * SENT  + tp) * D_;
    const u16*   lrow = logits_g + ((size_t)b * SLOTB + tp) * D_;
    float rv[16];
    #pragma unroll
    for (int i = 0; i < 8; ++i) rv[i]     = nrow[lane + i * 64];
    #pragma unroll
    for (int i = 0; i < 8; ++i) rv[8 + i] = b2f(lrow[lane + i * 64]);
    for (int j = 0; j < NERL; ++j) {
      float s = 0.f;
      #pragma unroll
      for (int i = 0; i < 16; ++i)
        s = fmaf(rv[i], nw[(size_t)(lane + i * 64) * NERL + j], s);
      for (int o = 32; o > 0; o >>= 1) s += __shfl_down(s, o);
      if (lane == 0) outp[r * NERL + j] = s + nb[j];
    }
  } else {
    const int p = blockIdx.x - 96;
    const u16* r0 = logits_g + (size_t)pslot[p] * D_;   // 4 consecutive slots
    for (int dd = threadIdx.x; dd < D_; dd += 256)
      avg[dd] = 0.25f * (b2f(r0[dd]) + b2f(r0[D_ + dd]) +
                         b2f(r0[2 * D_ + dd]) + b2f(r0[3 * D_ + dd]));
    __syncthreads();
    const int wave = threadIdx.x >> 6, lane = threadIdx.x & 63;
    const float* rf = refeat + (size_t)p * D_;
    float* out = outp + B_ * SENT * NERL;
    for (int jj = 0; jj < 8; ++jj) {
      int j = wave * 8 + jj;
      float s = 0.f;
      #pragma unroll
      for (int i = 0; i < 8; ++i) {
        int k = lane + i * 64;
        s = fmaf(rf[k],  rw[(size_t)k * REL + j], s);
        s = fmaf(avg[k], rw[(size_t)(k + D_) * REL + j], s);
      }
      for (int o = 32; o > 0; o >>= 1) s += __shfl_down(s, o);
      if (lane == 0) out[p * REL + j] = s + rb[j];
    }
  }
}

// --------------------------------------------------------------- launch ----
extern "C" void kernel_launch(void* const* d_in, const int* in_sizes, int n_in,
                              void* d_out, int out_size, void* d_ws, size_t ws_size,
                              hipStream_t stream) {
  const float* inputs = (const float*)d_in[0];
  const float* ner    = (const float*)d_in[1];
  const float* refeat = (const float*)d_in[2];
  const float* adj    = (const float*)d_in[3];
  const float* W0w    = (const float*)d_in[4];
  const float* W0b    = (const float*)d_in[5];
  const float* W1w    = (const float*)d_in[6];
  const float* W1b    = (const float*)d_in[7];
  const float* outw   = (const float*)d_in[8];
  const float* outb   = (const float*)d_in[9];
  const float* nerw   = (const float*)d_in[10];
  const float* nerb   = (const float*)d_in[11];
  const float* rew    = (const float*)d_in[12];
  const float* reb    = (const float*)d_in[13];
  const int*   ps     = (const int*)d_in[14];
  const int*   hs     = (const int*)d_in[15];
  const int*   ts     = (const int*)d_in[16];
  (void)in_sizes; (void)n_in; (void)out_size; (void)ws_size;
  float* outp = (float*)d_out;

  char* ws = (char*)d_ws;
  size_t off = 0;
  u8* adj8 = (u8*)(ws + off); off += (size_t)B_ * NP * NP;        // 44.3 MB
  float* rdenom = (float*)(ws + off); off += (size_t)MTOT * 4;
  u16* zp  = (u16*)(ws + off); off += 1024;
  u16* w0t = (u16*)(ws + off); off += 512 * 512 * 2;
  u16* w1t = (u16*)(ws + off); off += 512 * 512 * 2;
  u16* owt = (u16*)(ws + off); off += 512 * 1024 * 2;
  u8*  xt8 = (u8*)(ws + off); off += (size_t)B_ * 512 * NP;       // x^T8 / g0^T8
  u16* S   = (u16*)(ws + off); off += (size_t)MTOT * 512 * 2;
  u16* g0  = (u16*)(ws + off); off += (size_t)MTOT * 512 * 2;
  int* rowmap = (int*)(ws + off); off += (size_t)MG * 4;
  int* pslot  = (int*)(ws + off); off += (size_t)PAIRS * 4;
  u16* S_g      = (u16*)(ws + off); off += (size_t)MG * 512 * 2;
  u16* g1_g     = (u16*)(ws + off); off += (size_t)MG * 512 * 2;
  u16* logits_g = (u16*)(ws + off); off += (size_t)MG * 512 * 2;

  // one fat prep dispatch: adj8+rdenom, zp, rowmap/pslot, all 4 transposes
  const int FATG = ADJB + 2 + 2368 + 64 + 64 + 128;   // 7330
  fat_prep<<<FATG, 256, 0, stream>>>(adj, inputs, W0w, W1w, outw, ps, hs, ts,
                                     adj8, rdenom, xt8, w0t, w1t, owt,
                                     rowmap, pslot, zp);

  // Layer 1: S = adj@x + x (fp8); g0 = relu((S@W0+2b)/denom) (+ g0^T fp8*32)
  gemm8<0,0,0><<<608, 256, 0, stream>>>(adj8, nullptr, xt8, nullptr,
                                        nullptr, nullptr, nullptr, zp, S,
                                        nullptr, 1.0f);
  gemm8<1,1,0><<<588, 256, 0, stream>>>(S, nullptr, w0t, nullptr,
                                        W0b, rdenom, nullptr, zp, g0,
                                        xt8, 1.0f);
  // Layer 2 (gathered, M = 5120 slots)
  gemm8<0,0,1><<<160, 256, 0, stream>>>(adj8, nullptr, xt8, g0,
                                        nullptr, rdenom, rowmap, zp, S_g,
                                        nullptr, 1.0f / GSCALE);
  gemm8<1,0,1><<<160, 256, 0, stream>>>(S_g, nullptr, w1t, nullptr,
                                        W1b, rdenom, rowmap, zp, g1_g,
                                        nullptr, 1.0f);
  gemm8<2,0,1><<<160, 256, 0, stream>>>(g0, g1_g, owt, nullptr,
                                        outb, nullptr, rowmap, zp, logits_g,
                                        nullptr, 1.0f);

  heads_kernel<<<608, 256, 0, stream>>>(ner, logits_g, nerw, nerb,
                                        refeat, rew, reb, pslot, outp);
}